// Round 5
// baseline (129.345 us; speedup 1.0000x reference)
//
#include <hip/hip_runtime.h>
#include <hip/hip_bf16.h>
#include <cstdint>
#include <cstddef>

// ---------------------------------------------------------------------------
// out = softmax(Q K^T / 128) V, N=M=8192, d=128, fp32 in/out.
// Round 7: kill the residual spill. qb-SEQUENTIAL QK (one 16-reg sc ever
// live; K frags re-read for qb1) + sched_barrier(0) fences at every phase
// boundary (program-order liveness = actual peak ~232 <= 256) + SGB
// [1 DS, 1|2 MFMA] inside clusters. Geometry unchanged: 64 q/wave,
// NSPLIT=16, dbuf staging, in-register P pack, setprio on MFMA clusters.
// ---------------------------------------------------------------------------

typedef __attribute__((ext_vector_type(8))) short short8;     // 8 bf16
typedef __attribute__((ext_vector_type(4))) short shortx4;    // 4 bf16
typedef __attribute__((ext_vector_type(4))) float floatx4;
typedef __attribute__((ext_vector_type(16))) float floatx16;
typedef __attribute__((ext_vector_type(8))) _Float16 half8;

#define N_Q    8192
#define N_KV   8192
#define DHEAD  128
#define NSPLIT 16
#define BK     64
// fold 1/128 scaling and log2(e) into Q: scores in exp2 domain
#define QSCALE (1.4426950408889634f / 128.0f)

static __device__ __forceinline__ unsigned short f2bf(float x) {
  __hip_bfloat16 h = __float2bfloat16(x);
  unsigned short u;
  __builtin_memcpy(&u, &h, 2);
  return u;
}

// packed f32x2 -> bf16x2 (single HW instr; no builtin on gfx950)
static __device__ __forceinline__ uint32_t cvt_pk_bf16(float lo, float hi) {
  uint32_t r;
  asm("v_cvt_pk_bf16_f32 %0, %1, %2" : "=v"(r) : "v"(lo), "v"(hi));
  return r;
}

#define MFMA32(a, b, c) __builtin_amdgcn_mfma_f32_32x32x16_bf16((a), (b), (c), 0, 0, 0)

#define GLD_LDS16(g, l)                                                        \
  __builtin_amdgcn_global_load_lds(                                            \
      (const __attribute__((address_space(1))) void*)(g),                      \
      (__attribute__((address_space(3))) void*)(l), 16, 0, 0)

// LLVM SchedGroupMask: MFMA=0x8, DS_READ=0x100
#define SGB_QK()                                                               \
  _Pragma("unroll")                                                            \
  for (int _i = 0; _i < 8; ++_i) {                                             \
    __builtin_amdgcn_sched_group_barrier(0x100, 1, 0);                         \
    __builtin_amdgcn_sched_group_barrier(0x008, 1, 0);                         \
  }
#define SGB_PV()                                                               \
  _Pragma("unroll")                                                            \
  for (int _i = 0; _i < 8; ++_i) {                                             \
    __builtin_amdgcn_sched_group_barrier(0x100, 1, 0);                         \
    __builtin_amdgcn_sched_group_barrier(0x008, 2, 0);                         \
  }

// ---------------------------------------------------------------------------
// Fused convert kernel (unchanged).
// Blocks [0,512):   K[8192][128] f32 -> Kbc chunk-major bf16:
//   ((b*16 + ch)*64 + ki)*8 + j == bf16(K[b*64+ki][ch*8+j])
// Blocks [512,1536): V[8192][128] f32 -> Vtc transposed chunk-major bf16:
//   ((b*8 + c2)*128 + dv)*8 + kk == bf16(V[b*64 + c2*8 + kk][dv])
// ---------------------------------------------------------------------------
__global__ void cvt_kernel(const float* __restrict__ K,
                           const float* __restrict__ V,
                           unsigned short* __restrict__ Kbc,
                           unsigned short* __restrict__ Vtc) {
  int bid = blockIdx.x;
  if (bid < 512) {
    int tid = bid * 256 + threadIdx.x;  // 131072 threads, 16B out each
    int ki = tid & 63;
    int ch = (tid >> 6) & 15;
    int b  = tid >> 10;
    const float* src = K + ((size_t)(b * 64 + ki) * DHEAD + ch * 8);
    floatx4 f0 = *(const floatx4*)src;
    floatx4 f1 = *(const floatx4*)(src + 4);
    short8 o;
    o[0] = (short)f2bf(f0[0]); o[1] = (short)f2bf(f0[1]);
    o[2] = (short)f2bf(f0[2]); o[3] = (short)f2bf(f0[3]);
    o[4] = (short)f2bf(f1[0]); o[5] = (short)f2bf(f1[1]);
    o[6] = (short)f2bf(f1[2]); o[7] = (short)f2bf(f1[3]);
    *(short8*)(Kbc + (size_t)tid * 8) = o;
  } else {
    int tid = (bid - 512) * 256 + threadIdx.x;  // 262144 threads, 8B out each
    int kh = tid & 1;
    int dv = (tid >> 1) & 127;
    int c2 = (tid >> 8) & 7;
    int b  = tid >> 11;
    int k0 = b * 64 + c2 * 8 + kh * 4;
    shortx4 o;
    o[0] = (short)f2bf(V[(size_t)(k0 + 0) * DHEAD + dv]);
    o[1] = (short)f2bf(V[(size_t)(k0 + 1) * DHEAD + dv]);
    o[2] = (short)f2bf(V[(size_t)(k0 + 2) * DHEAD + dv]);
    o[3] = (short)f2bf(V[(size_t)(k0 + 3) * DHEAD + dv]);
    *(shortx4*)(Vtc + (size_t)tid * 4) = o;
  }
}

// ---------------------------------------------------------------------------
// Flash attention, 32x32x16 MFMA, no max-shift (scores bounded ~|1|).
// Block = 256 threads (4 waves); wave w owns queries
// [blockIdx.x*256 + w*64, +64) as 2 sub-blocks of 32; split blockIdx.y owns
// keys [sp*512, +512) in 8 tiles of 64, double-buffered in LDS.
// Register budget @ 2 waves/SIMD = 256 (unified VGPR/AGPR):
//   acc 128 | qf 64 | sc 16 (ONE live: qb-sequential) | pa 8-16 | misc ~16.
// sched_barrier(0) at phase boundaries pins program-order liveness.
// ---------------------------------------------------------------------------
__global__ __launch_bounds__(256, 2) void attn_kernel(
    const float* __restrict__ Q, const unsigned short* __restrict__ Kbc,
    const unsigned short* __restrict__ Vtc, _Float16* __restrict__ Opart,
    float* __restrict__ Lst) {
  // double buffer: [buf][ Ks 8192 shorts | Vts 8192 shorts ]  = 64 KiB
  __shared__ unsigned short lds[2 * 16384];

  const int t = threadIdx.x;
  const int w = t >> 6;
  const int lane = t & 63;
  const int h = lane >> 5;  // half 0/1
  const int c = lane & 31;  // 0..31
  const int qbase = blockIdx.x * 256 + w * 64;
  const int sp = blockIdx.y;

  // Q B-frags: B[k=d][n=q]; lane: n = c (query in sub-block), k = h*8+j.
  short8 qf[2][8];
#pragma unroll
  for (int qb = 0; qb < 2; ++qb) {
    const float* qrow = Q + (size_t)(qbase + qb * 32 + c) * DHEAD + h * 8;
#pragma unroll
    for (int dc = 0; dc < 8; ++dc) {
      floatx4 f0 = *(const floatx4*)(qrow + dc * 16);
      floatx4 f1 = *(const floatx4*)(qrow + dc * 16 + 4);
      short8 s;
      s[0] = (short)f2bf(f0[0] * QSCALE); s[1] = (short)f2bf(f0[1] * QSCALE);
      s[2] = (short)f2bf(f0[2] * QSCALE); s[3] = (short)f2bf(f0[3] * QSCALE);
      s[4] = (short)f2bf(f1[0] * QSCALE); s[5] = (short)f2bf(f1[1] * QSCALE);
      s[6] = (short)f2bf(f1[2] * QSCALE); s[7] = (short)f2bf(f1[3] * QSCALE);
      qf[qb][dc] = s;
    }
  }

  // O accum: C layout: col dv = nb*32+c, row q = (r&3)+8*(r>>2)+4h
  floatx16 acc0[4], acc1[4];
#pragma unroll
  for (int i = 0; i < 4; ++i)
#pragma unroll
    for (int r = 0; r < 16; ++r) { acc0[i][r] = 0.f; acc1[i][r] = 0.f; }
  float lsum0 = 0.f, lsum1 = 0.f;

  const int NT = N_KV / NSPLIT / BK;  // 8
  const int kb0 = sp * NT;

  // stage tile kb into buffer at dstK (Ks | Vts): 16 x 1KB slabs each
  auto stage = [&](unsigned short* dstK, int kb) {
    const unsigned short* kg = Kbc + (size_t)kb * 8192;
    const unsigned short* vg = Vtc + (size_t)kb * 8192;
#pragma unroll
    for (int i = 0; i < 4; ++i) {
      int slab = w * 4 + i;  // wave-uniform
      GLD_LDS16(kg + slab * 512 + lane * 8, dstK + slab * 512);
      GLD_LDS16(vg + slab * 512 + lane * 8, dstK + 8192 + slab * 512);
    }
  };

  // exp2 + pack 8 scores (sc[g..g+7]) into one bf16 A-frag; accumulates lsum.
  auto pack8 = [&](const floatx16& sc, int g, float& lsum) -> short8 {
    float p0 = __builtin_amdgcn_exp2f(sc[g + 0]);
    float p1 = __builtin_amdgcn_exp2f(sc[g + 1]);
    float p2 = __builtin_amdgcn_exp2f(sc[g + 2]);
    float p3 = __builtin_amdgcn_exp2f(sc[g + 3]);
    float p4 = __builtin_amdgcn_exp2f(sc[g + 4]);
    float p5 = __builtin_amdgcn_exp2f(sc[g + 5]);
    float p6 = __builtin_amdgcn_exp2f(sc[g + 6]);
    float p7 = __builtin_amdgcn_exp2f(sc[g + 7]);
    lsum += ((p0 + p1) + (p2 + p3)) + ((p4 + p5) + (p6 + p7));
    uint32_t x0 = cvt_pk_bf16(p0, p1);
    uint32_t x1 = cvt_pk_bf16(p2, p3);
    uint32_t y0 = cvt_pk_bf16(p4, p5);
    uint32_t y1 = cvt_pk_bf16(p6, p7);
    auto s0 = __builtin_amdgcn_permlane32_swap(x0, y0, false, false);
    auto s1 = __builtin_amdgcn_permlane32_swap(x1, y1, false, false);
    union { uint32_t u[4]; short8 s; } pu;
    pu.u[0] = s0[0]; pu.u[1] = s1[0]; pu.u[2] = s0[1]; pu.u[3] = s1[1];
    return pu.s;
  };

  stage(lds, kb0);
  __syncthreads();

  for (int it = 0; it < NT; ++it) {
    const int cur = it & 1;
    // issue next tile's loads BEFORE compute; vmcnt drains at loop barrier
    if (it + 1 < NT) stage(lds + (cur ^ 1) * 16384, kb0 + it + 1);

    const short8* KsF  = (const short8*)(lds + cur * 16384);
    const short8* VtsF = (const short8*)(lds + cur * 16384 + 8192);

#pragma unroll
    for (int st = 0; st < 2; ++st) {
      // ======== qb0: QK then pack (sc dies before qb1) ========
      floatx16 sc;
#pragma unroll
      for (int r = 0; r < 16; ++r) sc[r] = 0.f;
      __builtin_amdgcn_s_setprio(1);
#pragma unroll
      for (int dc = 0; dc < 8; ++dc) {
        short8 ka = KsF[(dc * 2 + h) * 64 + st * 32 + c];  // key = st*32+c
        sc = MFMA32(ka, qf[0][dc], sc);
      }
      SGB_QK();
      __builtin_amdgcn_s_setprio(0);
      __builtin_amdgcn_sched_barrier(0);
      // lane = col q=c, rows key = st*32 + (r&3)+8*(r>>2)+4h
      short8 pa00 = pack8(sc, 0, lsum0);
      short8 pa01 = pack8(sc, 8, lsum0);
      __builtin_amdgcn_sched_barrier(0);

      // ======== qb1: QK then pack (K frags re-read; sc reused) ========
#pragma unroll
      for (int r = 0; r < 16; ++r) sc[r] = 0.f;
      __builtin_amdgcn_s_setprio(1);
#pragma unroll
      for (int dc = 0; dc < 8; ++dc) {
        short8 ka = KsF[(dc * 2 + h) * 64 + st * 32 + c];
        sc = MFMA32(ka, qf[1][dc], sc);
      }
      SGB_QK();
      __builtin_amdgcn_s_setprio(0);
      __builtin_amdgcn_sched_barrier(0);
      short8 pa10 = pack8(sc, 0, lsum1);
      short8 pa11 = pack8(sc, 8, lsum1);
      __builtin_amdgcn_sched_barrier(0);

      // ======== PV joint: O += P.V (V frags shared across q-blocks) ========
      __builtin_amdgcn_s_setprio(1);
#pragma unroll
      for (int kc2 = 0; kc2 < 2; ++kc2) {
        const int kc = st * 2 + kc2;
        const short8 a0 = kc2 ? pa01 : pa00;
        const short8 a1 = kc2 ? pa11 : pa10;
#pragma unroll
        for (int nb = 0; nb < 4; ++nb) {
          short8 bv = VtsF[(kc * 2 + h) * 128 + nb * 32 + c];  // V[key][dv]
          acc0[nb] = MFMA32(a0, bv, acc0[nb]);
          acc1[nb] = MFMA32(a1, bv, acc1[nb]);
        }
      }
      SGB_PV();
      __builtin_amdgcn_s_setprio(0);
      __builtin_amdgcn_sched_barrier(0);
    }
    __syncthreads();  // all waves done with buf[cur]; next stage may overwrite
  }

  // ---- epilogue ----
  {
    float l0 = lsum0 + __shfl_xor(lsum0, 32, 64);
    float l1 = lsum1 + __shfl_xor(lsum1, 32, 64);
    if (h == 0) {
      Lst[(size_t)sp * N_Q + qbase + c] = l0;
      Lst[(size_t)sp * N_Q + qbase + 32 + c] = l1;
    }
  }
  _Float16* op0 = Opart + ((size_t)sp * N_Q + qbase) * DHEAD;
  _Float16* op1 = Opart + ((size_t)sp * N_Q + qbase + 32) * DHEAD;
#pragma unroll
  for (int nb = 0; nb < 4; ++nb)
#pragma unroll
    for (int r = 0; r < 16; ++r) {
      int row = (r & 3) + 8 * (r >> 2) + 4 * h;
      op0[(size_t)row * DHEAD + nb * 32 + c] = (_Float16)acc0[nb][r];
      op1[(size_t)row * DHEAD + nb * 32 + c] = (_Float16)acc1[nb][r];
    }
}

// ---------------------------------------------------------------------------
// Merge: out[g][dv] = sum_s O_s[g][dv] / sum_s l_s[g]. 131072 threads,
// 8 dv each (16B fp16 loads).
// ---------------------------------------------------------------------------
__global__ void merge_kernel(const _Float16* __restrict__ Opart,
                             const float* __restrict__ Lst,
                             float* __restrict__ out) {
  int tid = blockIdx.x * blockDim.x + threadIdx.x;
  int g = tid >> 4;
  int d0 = (tid & 15) * 8;
  float den = 0.f;
  float num[8] = {0.f, 0.f, 0.f, 0.f, 0.f, 0.f, 0.f, 0.f};
#pragma unroll
  for (int s = 0; s < NSPLIT; ++s) {
    den += Lst[(size_t)s * N_Q + g];
    half8 o = *(const half8*)(Opart + ((size_t)s * N_Q + g) * DHEAD + d0);
#pragma unroll
    for (int j = 0; j < 8; ++j) num[j] += (float)o[j];
  }
  float inv = 1.0f / den;
  floatx4 r0 = (floatx4){num[0] * inv, num[1] * inv, num[2] * inv, num[3] * inv};
  floatx4 r1 = (floatx4){num[4] * inv, num[5] * inv, num[6] * inv, num[7] * inv};
  float* dst = out + (size_t)g * DHEAD + d0;
  *(floatx4*)dst = r0;
  *(floatx4*)(dst + 4) = r1;
}

// ---------------------------------------------------------------------------
extern "C" void kernel_launch(void* const* d_in, const int* in_sizes, int n_in,
                              void* d_out, int out_size, void* d_ws,
                              size_t ws_size, hipStream_t stream) {
  const float* Q = (const float*)d_in[0];
  const float* K = (const float*)d_in[1];
  const float* V = (const float*)d_in[2];
  float* out = (float*)d_out;

  char* ws = (char*)d_ws;
  // Kbc 2MiB | Vtc 2MiB | Opart fp16 32MiB | Lst 512KiB  (= 36.5MiB total)
  unsigned short* Kbc = (unsigned short*)(ws);
  unsigned short* Vtc = (unsigned short*)(ws + (2u << 20));
  _Float16* Opart = (_Float16*)(ws + (4u << 20));
  float* Lst = (float*)(ws + (36u << 20));

  cvt_kernel<<<dim3(1536), dim3(256), 0, stream>>>(K, V, Kbc, Vtc);
  attn_kernel<<<dim3(N_Q / 256, NSPLIT), dim3(256), 0, stream>>>(Q, Kbc, Vtc,
                                                                 Opart, Lst);
  merge_kernel<<<dim3(512), dim3(256), 0, stream>>>(Opart, Lst, out);
}

// Round 6
// 114.398 us; speedup vs baseline: 1.1307x; 1.1307x over previous
//
#include <hip/hip_runtime.h>
#include <hip/hip_bf16.h>
#include <cstdint>
#include <cstddef>

// ---------------------------------------------------------------------------
// out = softmax(Q K^T / 128) V, N=M=8192, d=128, fp32 in/out.
// Round 8: revert to spill-free 32 q/wave dataflow (round-1), attack the
// latency-boundness with OCCUPANCY: BK=32 (dbuf LDS 32KB/block) + NSPLIT=16
// (grid 1024 = 4 blocks/CU = 4 waves/SIMD, launch_bounds(256,4)).
// K/V pre-tiled per 32-key block so staging stays linear global_load_lds.
// No sched_group_barrier / sched_barrier (rounds 6-7 proved harmful).
// ---------------------------------------------------------------------------

typedef __attribute__((ext_vector_type(8))) short short8;     // 8 bf16
typedef __attribute__((ext_vector_type(4))) short shortx4;    // 4 bf16
typedef __attribute__((ext_vector_type(4))) float floatx4;
typedef __attribute__((ext_vector_type(16))) float floatx16;
typedef __attribute__((ext_vector_type(8))) _Float16 half8;

#define N_Q    8192
#define N_KV   8192
#define DHEAD  128
#define NSPLIT 16
#define BK     32
// fold 1/128 scaling and log2(e) into Q: scores in exp2 domain
#define QSCALE (1.4426950408889634f / 128.0f)

static __device__ __forceinline__ unsigned short f2bf(float x) {
  __hip_bfloat16 h = __float2bfloat16(x);
  unsigned short u;
  __builtin_memcpy(&u, &h, 2);
  return u;
}

// packed f32x2 -> bf16x2 (single HW instr; no builtin on gfx950)
static __device__ __forceinline__ uint32_t cvt_pk_bf16(float lo, float hi) {
  uint32_t r;
  asm("v_cvt_pk_bf16_f32 %0, %1, %2" : "=v"(r) : "v"(lo), "v"(hi));
  return r;
}

#define MFMA32(a, b, c) __builtin_amdgcn_mfma_f32_32x32x16_bf16((a), (b), (c), 0, 0, 0)

#define GLD_LDS16(g, l)                                                        \
  __builtin_amdgcn_global_load_lds(                                            \
      (const __attribute__((address_space(1))) void*)(g),                      \
      (__attribute__((address_space(3))) void*)(l), 16, 0, 0)

// ---------------------------------------------------------------------------
// Fused convert kernel — 32-key-tile layouts.
// Blocks [0,512):   K[8192][128] f32 -> Kbc chunk-major bf16 per 32-key tile:
//   ((b32*16 + ch)*32 + ki)*8 + j == bf16(K[b32*32+ki][ch*8+j])
// Blocks [512,1536): V[8192][128] f32 -> Vtc transposed per 32-key tile:
//   ((b32*4 + c2)*128 + dv)*8 + kk == bf16(V[b32*32 + c2*8 + kk][dv])
// ---------------------------------------------------------------------------
__global__ void cvt_kernel(const float* __restrict__ K,
                           const float* __restrict__ V,
                           unsigned short* __restrict__ Kbc,
                           unsigned short* __restrict__ Vtc) {
  int bid = blockIdx.x;
  if (bid < 512) {
    int tid = bid * 256 + threadIdx.x;  // 131072 threads, 16B out each
    int ki  = tid & 31;
    int ch  = (tid >> 5) & 15;
    int b32 = tid >> 9;
    const float* src = K + ((size_t)(b32 * 32 + ki) * DHEAD + ch * 8);
    floatx4 f0 = *(const floatx4*)src;
    floatx4 f1 = *(const floatx4*)(src + 4);
    short8 o;
    o[0] = (short)f2bf(f0[0]); o[1] = (short)f2bf(f0[1]);
    o[2] = (short)f2bf(f0[2]); o[3] = (short)f2bf(f0[3]);
    o[4] = (short)f2bf(f1[0]); o[5] = (short)f2bf(f1[1]);
    o[6] = (short)f2bf(f1[2]); o[7] = (short)f2bf(f1[3]);
    *(short8*)(Kbc + (size_t)tid * 8) = o;
  } else {
    int tid = (bid - 512) * 256 + threadIdx.x;  // 262144 threads, 8B out each
    int kh  = tid & 1;
    int dv  = (tid >> 1) & 127;
    int c2  = (tid >> 8) & 3;
    int b32 = tid >> 10;
    int k0 = b32 * 32 + c2 * 8 + kh * 4;
    shortx4 o;
    o[0] = (short)f2bf(V[(size_t)(k0 + 0) * DHEAD + dv]);
    o[1] = (short)f2bf(V[(size_t)(k0 + 1) * DHEAD + dv]);
    o[2] = (short)f2bf(V[(size_t)(k0 + 2) * DHEAD + dv]);
    o[3] = (short)f2bf(V[(size_t)(k0 + 3) * DHEAD + dv]);
    *(shortx4*)(Vtc + (size_t)tid * 4) = o;
  }
}

// ---------------------------------------------------------------------------
// Flash attention, 32x32x16 MFMA, no max-shift (scores bounded ~|1|).
// Block = 256 threads (4 waves); wave w owns queries [blockIdx.x*128+w*32,+32);
// split blockIdx.y owns keys [sp*512, +512) in 16 tiles of 32, dbuf in LDS.
// 4 blocks/CU (LDS 32KB, grid 1024) -> 4 waves/SIMD latency hiding.
// Per tile: S^T = K.Q^T (8 d-chunk MFMAs), p = exp2(s), in-register P pack
// (cvt_pk + permlane32_swap), O += P.V (2 kchunks x 4 dv-subtiles).
// ---------------------------------------------------------------------------
__global__ __launch_bounds__(256, 4) void attn_kernel(
    const float* __restrict__ Q, const unsigned short* __restrict__ Kbc,
    const unsigned short* __restrict__ Vtc, _Float16* __restrict__ Opart,
    float* __restrict__ Lst) {
  // double buffer: [buf][ Ks 4096 shorts | Vts 4096 shorts ]  = 32 KiB
  __shared__ unsigned short lds[2 * 8192];

  const int t = threadIdx.x;
  const int w = t >> 6;
  const int lane = t & 63;
  const int h = lane >> 5;  // half 0/1
  const int c = lane & 31;  // 0..31
  const int qbase = blockIdx.x * 128 + w * 32;
  const int sp = blockIdx.y;

  // Q B-frags: B[k=d][n=q]; lane: n = c (query), k = (h*8 + j) within chunk.
  short8 qf[8];
  {
    const float* qrow = Q + (size_t)(qbase + c) * DHEAD + h * 8;
#pragma unroll
    for (int dc = 0; dc < 8; ++dc) {
      floatx4 f0 = *(const floatx4*)(qrow + dc * 16);
      floatx4 f1 = *(const floatx4*)(qrow + dc * 16 + 4);
      short8 s;
      s[0] = (short)f2bf(f0[0] * QSCALE); s[1] = (short)f2bf(f0[1] * QSCALE);
      s[2] = (short)f2bf(f0[2] * QSCALE); s[3] = (short)f2bf(f0[3] * QSCALE);
      s[4] = (short)f2bf(f1[0] * QSCALE); s[5] = (short)f2bf(f1[1] * QSCALE);
      s[6] = (short)f2bf(f1[2] * QSCALE); s[7] = (short)f2bf(f1[3] * QSCALE);
      qf[dc] = s;
    }
  }

  // O accum: C layout: col dv = nb*32 + c, row q = (r&3)+8*(r>>2)+4*h
  floatx16 acc[4];
#pragma unroll
  for (int i = 0; i < 4; ++i)
#pragma unroll
    for (int r = 0; r < 16; ++r) acc[i][r] = 0.f;
  float lsum = 0.f;

  const int NT = N_KV / NSPLIT / BK;  // 16 tiles of 32 keys
  const int kb0 = sp * NT;

  // stage 32-key tile kb into buffer at dstK (Ks 8KB | Vts 8KB):
  // 8+8 slabs of 1KB, 2+2 per wave.
  auto stage = [&](unsigned short* dstK, int kb) {
    const unsigned short* kg = Kbc + (size_t)kb * 4096;
    const unsigned short* vg = Vtc + (size_t)kb * 4096;
#pragma unroll
    for (int i = 0; i < 2; ++i) {
      int slab = w * 2 + i;  // wave-uniform, 0..7
      GLD_LDS16(kg + slab * 512 + lane * 8, dstK + slab * 512);
      GLD_LDS16(vg + slab * 512 + lane * 8, dstK + 4096 + slab * 512);
    }
  };

  // exp2 + pack 8 scores (sc[g..g+7]) into one bf16 A-frag; accumulates lsum.
  auto pack8 = [&](const floatx16& sc, int g, float& ls) -> short8 {
    float p0 = __builtin_amdgcn_exp2f(sc[g + 0]);
    float p1 = __builtin_amdgcn_exp2f(sc[g + 1]);
    float p2 = __builtin_amdgcn_exp2f(sc[g + 2]);
    float p3 = __builtin_amdgcn_exp2f(sc[g + 3]);
    float p4 = __builtin_amdgcn_exp2f(sc[g + 4]);
    float p5 = __builtin_amdgcn_exp2f(sc[g + 5]);
    float p6 = __builtin_amdgcn_exp2f(sc[g + 6]);
    float p7 = __builtin_amdgcn_exp2f(sc[g + 7]);
    ls += ((p0 + p1) + (p2 + p3)) + ((p4 + p5) + (p6 + p7));
    uint32_t x0 = cvt_pk_bf16(p0, p1);
    uint32_t x1 = cvt_pk_bf16(p2, p3);
    uint32_t y0 = cvt_pk_bf16(p4, p5);
    uint32_t y1 = cvt_pk_bf16(p6, p7);
    auto s0 = __builtin_amdgcn_permlane32_swap(x0, y0, false, false);
    auto s1 = __builtin_amdgcn_permlane32_swap(x1, y1, false, false);
    union { uint32_t u[4]; short8 s; } pu;
    pu.u[0] = s0[0]; pu.u[1] = s1[0]; pu.u[2] = s0[1]; pu.u[3] = s1[1];
    return pu.s;
  };

  stage(lds, kb0);
  __syncthreads();

  for (int it = 0; it < NT; ++it) {
    const int cur = it & 1;
    // issue next tile's loads BEFORE compute; vmcnt drains at loop barrier
    if (it + 1 < NT) stage(lds + (cur ^ 1) * 8192, kb0 + it + 1);

    const short8* KsF  = (const short8*)(lds + cur * 8192);
    const short8* VtsF = (const short8*)(lds + cur * 8192 + 4096);

    // ---- S^T = K.Q^T (32 keys x 32 queries), K-frags transient ----
    floatx16 sc;
#pragma unroll
    for (int r = 0; r < 16; ++r) sc[r] = 0.f;
    __builtin_amdgcn_s_setprio(1);
#pragma unroll
    for (int dc = 0; dc < 8; ++dc) {
      short8 ka = KsF[(dc * 2 + h) * 32 + c];  // key = c, d-chunk dc*2+h
      sc = MFMA32(ka, qf[dc], sc);
    }
    __builtin_amdgcn_s_setprio(0);

    // ---- softmax + in-register pack ----
    // lane holds col q=c, rows key = (r&3)+8*(r>>2)+4*h
    short8 pa0 = pack8(sc, 0, lsum);  // keys  0..15 A-frag
    short8 pa1 = pack8(sc, 8, lsum);  // keys 16..31 A-frag

    // ---- O += P.V ----
    __builtin_amdgcn_s_setprio(1);
#pragma unroll
    for (int kc = 0; kc < 2; ++kc) {
      const short8 a = kc ? pa1 : pa0;
#pragma unroll
      for (int nb = 0; nb < 4; ++nb) {
        short8 bv = VtsF[(kc * 2 + h) * 128 + nb * 32 + c];  // V[key][dv]
        acc[nb] = MFMA32(a, bv, acc[nb]);
      }
    }
    __builtin_amdgcn_s_setprio(0);

    __syncthreads();  // all waves done with buf[cur]; next stage may overwrite
  }

  // ---- epilogue ----
  lsum += __shfl_xor(lsum, 32, 64);
  if (h == 0) Lst[(size_t)sp * N_Q + qbase + c] = lsum;
  _Float16* op = Opart + ((size_t)sp * N_Q + qbase) * DHEAD;
#pragma unroll
  for (int nb = 0; nb < 4; ++nb)
#pragma unroll
    for (int r = 0; r < 16; ++r) {
      int row = (r & 3) + 8 * (r >> 2) + 4 * h;
      op[(size_t)row * DHEAD + nb * 32 + c] = (_Float16)acc[nb][r];
    }
}

// ---------------------------------------------------------------------------
// Merge: out[g][dv] = sum_s O_s[g][dv] / sum_s l_s[g]. 131072 threads,
// 8 dv each (16B fp16 loads).
// ---------------------------------------------------------------------------
__global__ void merge_kernel(const _Float16* __restrict__ Opart,
                             const float* __restrict__ Lst,
                             float* __restrict__ out) {
  int tid = blockIdx.x * blockDim.x + threadIdx.x;
  int g = tid >> 4;
  int d0 = (tid & 15) * 8;
  float den = 0.f;
  float num[8] = {0.f, 0.f, 0.f, 0.f, 0.f, 0.f, 0.f, 0.f};
#pragma unroll
  for (int s = 0; s < NSPLIT; ++s) {
    den += Lst[(size_t)s * N_Q + g];
    half8 o = *(const half8*)(Opart + ((size_t)s * N_Q + g) * DHEAD + d0);
#pragma unroll
    for (int j = 0; j < 8; ++j) num[j] += (float)o[j];
  }
  float inv = 1.0f / den;
  floatx4 r0 = (floatx4){num[0] * inv, num[1] * inv, num[2] * inv, num[3] * inv};
  floatx4 r1 = (floatx4){num[4] * inv, num[5] * inv, num[6] * inv, num[7] * inv};
  float* dst = out + (size_t)g * DHEAD + d0;
  *(floatx4*)dst = r0;
  *(floatx4*)(dst + 4) = r1;
}

// ---------------------------------------------------------------------------
extern "C" void kernel_launch(void* const* d_in, const int* in_sizes, int n_in,
                              void* d_out, int out_size, void* d_ws,
                              size_t ws_size, hipStream_t stream) {
  const float* Q = (const float*)d_in[0];
  const float* K = (const float*)d_in[1];
  const float* V = (const float*)d_in[2];
  float* out = (float*)d_out;

  char* ws = (char*)d_ws;
  // Kbc 2MiB | Vtc 2MiB | Opart fp16 32MiB | Lst 512KiB  (= 36.5MiB total)
  unsigned short* Kbc = (unsigned short*)(ws);
  unsigned short* Vtc = (unsigned short*)(ws + (2u << 20));
  _Float16* Opart = (_Float16*)(ws + (4u << 20));
  float* Lst = (float*)(ws + (36u << 20));

  cvt_kernel<<<dim3(1536), dim3(256), 0, stream>>>(K, V, Kbc, Vtc);
  attn_kernel<<<dim3(N_Q / 128, NSPLIT), dim3(256), 0, stream>>>(Q, Kbc, Vtc,
                                                                 Opart, Lst);
  merge_kernel<<<dim3(512), dim3(256), 0, stream>>>(Opart, Lst, out);
}

// Round 7
// 108.278 us; speedup vs baseline: 1.1946x; 1.0565x over previous
//
#include <hip/hip_runtime.h>
#include <hip/hip_bf16.h>
#include <cstdint>
#include <cstddef>

// ---------------------------------------------------------------------------
// out = softmax(Q K^T / 128) V, N=M=8192, d=128, fp32 in/out.
// Round 9: best geometry (round 1: BK=64, NSPLIT=8, 32q/wave, 2 blocks/CU,
// dbuf) + COUNTED-VMCNT pipeline: raw s_barrier + s_waitcnt vmcnt(8) (never
// 0 in-loop) so next-tile global_load_lds stays in flight across barriers
// (T3/T4, m218 recipe). QK accumulator split into 2 interleaved MFMA chains.
// No sched_group_barrier / sched_barrier (rounds 6-7 proved harmful).
// ---------------------------------------------------------------------------

typedef __attribute__((ext_vector_type(8))) short short8;     // 8 bf16
typedef __attribute__((ext_vector_type(4))) short shortx4;    // 4 bf16
typedef __attribute__((ext_vector_type(4))) float floatx4;
typedef __attribute__((ext_vector_type(16))) float floatx16;
typedef __attribute__((ext_vector_type(8))) _Float16 half8;

#define N_Q    8192
#define N_KV   8192
#define DHEAD  128
#define NSPLIT 8
#define BK     64
// fold 1/128 scaling and log2(e) into Q: scores in exp2 domain
#define QSCALE (1.4426950408889634f / 128.0f)

static __device__ __forceinline__ unsigned short f2bf(float x) {
  __hip_bfloat16 h = __float2bfloat16(x);
  unsigned short u;
  __builtin_memcpy(&u, &h, 2);
  return u;
}

// packed f32x2 -> bf16x2 (single HW instr; no builtin on gfx950)
static __device__ __forceinline__ uint32_t cvt_pk_bf16(float lo, float hi) {
  uint32_t r;
  asm("v_cvt_pk_bf16_f32 %0, %1, %2" : "=v"(r) : "v"(lo), "v"(hi));
  return r;
}

#define MFMA32(a, b, c) __builtin_amdgcn_mfma_f32_32x32x16_bf16((a), (b), (c), 0, 0, 0)

#define GLD_LDS16(g, l)                                                        \
  __builtin_amdgcn_global_load_lds(                                            \
      (const __attribute__((address_space(1))) void*)(g),                      \
      (__attribute__((address_space(3))) void*)(l), 16, 0, 0)

// ---------------------------------------------------------------------------
// Fused convert kernel (round-1 64-key-tile layouts).
// Blocks [0,512):   K[8192][128] f32 -> Kbc chunk-major bf16:
//   ((b*16 + ch)*64 + ki)*8 + j == bf16(K[b*64+ki][ch*8+j])
// Blocks [512,1536): V[8192][128] f32 -> Vtc transposed chunk-major bf16:
//   ((b*8 + c2)*128 + dv)*8 + kk == bf16(V[b*64 + c2*8 + kk][dv])
// ---------------------------------------------------------------------------
__global__ void cvt_kernel(const float* __restrict__ K,
                           const float* __restrict__ V,
                           unsigned short* __restrict__ Kbc,
                           unsigned short* __restrict__ Vtc) {
  int bid = blockIdx.x;
  if (bid < 512) {
    int tid = bid * 256 + threadIdx.x;  // 131072 threads, 16B out each
    int ki = tid & 63;
    int ch = (tid >> 6) & 15;
    int b  = tid >> 10;
    const float* src = K + ((size_t)(b * 64 + ki) * DHEAD + ch * 8);
    floatx4 f0 = *(const floatx4*)src;
    floatx4 f1 = *(const floatx4*)(src + 4);
    short8 o;
    o[0] = (short)f2bf(f0[0]); o[1] = (short)f2bf(f0[1]);
    o[2] = (short)f2bf(f0[2]); o[3] = (short)f2bf(f0[3]);
    o[4] = (short)f2bf(f1[0]); o[5] = (short)f2bf(f1[1]);
    o[6] = (short)f2bf(f1[2]); o[7] = (short)f2bf(f1[3]);
    *(short8*)(Kbc + (size_t)tid * 8) = o;
  } else {
    int tid = (bid - 512) * 256 + threadIdx.x;  // 262144 threads, 8B out each
    int kh = tid & 1;
    int dv = (tid >> 1) & 127;
    int c2 = (tid >> 8) & 7;
    int b  = tid >> 11;
    int k0 = b * 64 + c2 * 8 + kh * 4;
    shortx4 o;
    o[0] = (short)f2bf(V[(size_t)(k0 + 0) * DHEAD + dv]);
    o[1] = (short)f2bf(V[(size_t)(k0 + 1) * DHEAD + dv]);
    o[2] = (short)f2bf(V[(size_t)(k0 + 2) * DHEAD + dv]);
    o[3] = (short)f2bf(V[(size_t)(k0 + 3) * DHEAD + dv]);
    *(shortx4*)(Vtc + (size_t)tid * 4) = o;
  }
}

// ---------------------------------------------------------------------------
// Flash attention, 32x32x16 MFMA, no max-shift (scores bounded ~|1|).
// Block = 256 threads (4 waves); wave w owns queries [blockIdx.x*128+w*32,+32);
// split blockIdx.y owns keys [sp*1024, +1024) in 16 tiles of 64, dbuf in LDS.
// Pipeline: stage(t+1) -> s_waitcnt vmcnt(8) (tile-t loads done, t+1 still in
// flight) -> s_barrier -> compute(t) -> s_barrier. No full vmcnt drain.
// ---------------------------------------------------------------------------
__global__ __launch_bounds__(256, 2) void attn_kernel(
    const float* __restrict__ Q, const unsigned short* __restrict__ Kbc,
    const unsigned short* __restrict__ Vtc, _Float16* __restrict__ Opart,
    float* __restrict__ Lst) {
  // double buffer: [buf][ Ks 8192 shorts | Vts 8192 shorts ]  = 64 KiB
  __shared__ unsigned short lds[2 * 16384];

  const int t = threadIdx.x;
  const int w = t >> 6;
  const int lane = t & 63;
  const int h = lane >> 5;  // half 0/1
  const int c = lane & 31;  // 0..31
  const int qbase = blockIdx.x * 128 + w * 32;
  const int sp = blockIdx.y;

  // Q B-frags: B[k=d][n=q]; lane: n = c (query), k = (h*8 + j) within chunk.
  short8 qf[8];
  {
    const float* qrow = Q + (size_t)(qbase + c) * DHEAD + h * 8;
#pragma unroll
    for (int dc = 0; dc < 8; ++dc) {
      floatx4 f0 = *(const floatx4*)(qrow + dc * 16);
      floatx4 f1 = *(const floatx4*)(qrow + dc * 16 + 4);
      short8 s;
      s[0] = (short)f2bf(f0[0] * QSCALE); s[1] = (short)f2bf(f0[1] * QSCALE);
      s[2] = (short)f2bf(f0[2] * QSCALE); s[3] = (short)f2bf(f0[3] * QSCALE);
      s[4] = (short)f2bf(f1[0] * QSCALE); s[5] = (short)f2bf(f1[1] * QSCALE);
      s[6] = (short)f2bf(f1[2] * QSCALE); s[7] = (short)f2bf(f1[3] * QSCALE);
      qf[dc] = s;
    }
  }

  // O accum: C layout: col dv = nb*32 + c, row q = (r&3)+8*(r>>2)+4*h
  floatx16 acc[4];
#pragma unroll
  for (int i = 0; i < 4; ++i)
#pragma unroll
    for (int r = 0; r < 16; ++r) acc[i][r] = 0.f;
  float lsum = 0.f;

  const int NT = N_KV / NSPLIT / BK;  // 16
  const int kb0 = sp * NT;

  // stage tile kb into buffer at dstK (Ks | Vts): 16 x 1KB slabs each,
  // 4 K-loads + 4 V-loads per wave = 8 global_load_lds per wave.
  auto stage = [&](unsigned short* dstK, int kb) {
    const unsigned short* kg = Kbc + (size_t)kb * 8192;
    const unsigned short* vg = Vtc + (size_t)kb * 8192;
#pragma unroll
    for (int i = 0; i < 4; ++i) {
      int slab = w * 4 + i;  // wave-uniform
      GLD_LDS16(kg + slab * 512 + lane * 8, dstK + slab * 512);
      GLD_LDS16(vg + slab * 512 + lane * 8, dstK + 8192 + slab * 512);
    }
  };

  // exp2 + pack 8 scores (sc[g..g+7]) into one bf16 A-frag; accumulates lsum.
  auto pack8 = [&](const floatx16& sc, int g, float& ls) -> short8 {
    float p0 = __builtin_amdgcn_exp2f(sc[g + 0]);
    float p1 = __builtin_amdgcn_exp2f(sc[g + 1]);
    float p2 = __builtin_amdgcn_exp2f(sc[g + 2]);
    float p3 = __builtin_amdgcn_exp2f(sc[g + 3]);
    float p4 = __builtin_amdgcn_exp2f(sc[g + 4]);
    float p5 = __builtin_amdgcn_exp2f(sc[g + 5]);
    float p6 = __builtin_amdgcn_exp2f(sc[g + 6]);
    float p7 = __builtin_amdgcn_exp2f(sc[g + 7]);
    ls += ((p0 + p1) + (p2 + p3)) + ((p4 + p5) + (p6 + p7));
    uint32_t x0 = cvt_pk_bf16(p0, p1);
    uint32_t x1 = cvt_pk_bf16(p2, p3);
    uint32_t y0 = cvt_pk_bf16(p4, p5);
    uint32_t y1 = cvt_pk_bf16(p6, p7);
    auto s0 = __builtin_amdgcn_permlane32_swap(x0, y0, false, false);
    auto s1 = __builtin_amdgcn_permlane32_swap(x1, y1, false, false);
    union { uint32_t u[4]; short8 s; } pu;
    pu.u[0] = s0[0]; pu.u[1] = s1[0]; pu.u[2] = s0[1]; pu.u[3] = s1[1];
    return pu.s;
  };

  stage(lds, kb0);  // 8 loads in flight

  for (int it = 0; it < NT; ++it) {
    const int cur = it & 1;
    if (it + 1 < NT) {
      // issue next tile (8 more loads), then wait only for tile-it's 8:
      // outstanding after wait = 8 (tile it+1 stays in flight).
      stage(lds + (cur ^ 1) * 16384, kb0 + it + 1);
      asm volatile("s_waitcnt vmcnt(8)" ::: "memory");
    } else {
      asm volatile("s_waitcnt vmcnt(0)" ::: "memory");
    }
    __builtin_amdgcn_s_barrier();  // join: all waves' tile-it loads landed

    const short8* KsF  = (const short8*)(lds + cur * 16384);
    const short8* VtsF = (const short8*)(lds + cur * 16384 + 8192);

#pragma unroll
    for (int st = 0; st < 2; ++st) {
      // ---- S^T = K.Q^T, TWO interleaved accumulator chains ----
      floatx16 scE, scO;
#pragma unroll
      for (int r = 0; r < 16; ++r) { scE[r] = 0.f; scO[r] = 0.f; }
      __builtin_amdgcn_s_setprio(1);
#pragma unroll
      for (int j = 0; j < 4; ++j) {
        short8 kaE = KsF[((2 * j) * 2 + h) * 64 + st * 32 + c];
        short8 kaO = KsF[((2 * j + 1) * 2 + h) * 64 + st * 32 + c];
        scE = MFMA32(kaE, qf[2 * j], scE);
        scO = MFMA32(kaO, qf[2 * j + 1], scO);
      }
      __builtin_amdgcn_s_setprio(0);
      floatx16 sc;
#pragma unroll
      for (int r = 0; r < 16; ++r) sc[r] = scE[r] + scO[r];

      // ---- softmax + in-register pack ----
      // lane = col q=c, rows key = st*32 + (r&3)+8*(r>>2)+4*h
      short8 pa0 = pack8(sc, 0, lsum);
      short8 pa1 = pack8(sc, 8, lsum);

      // ---- O += P.V (4 independent acc chains) ----
      __builtin_amdgcn_s_setprio(1);
#pragma unroll
      for (int kc2 = 0; kc2 < 2; ++kc2) {
        const int kc = st * 2 + kc2;
        const short8 a = kc2 ? pa1 : pa0;
#pragma unroll
        for (int nb = 0; nb < 4; ++nb) {
          short8 bv = VtsF[(kc * 2 + h) * 128 + nb * 32 + c];  // V[key][dv]
          acc[nb] = MFMA32(a, bv, acc[nb]);
        }
      }
      __builtin_amdgcn_s_setprio(0);
    }
    __builtin_amdgcn_s_barrier();  // all waves done with buf[cur] before
                                   // next iteration's stage overwrites it
  }

  // ---- epilogue ----
  lsum += __shfl_xor(lsum, 32, 64);
  if (h == 0) Lst[(size_t)sp * N_Q + qbase + c] = lsum;
  _Float16* op = Opart + ((size_t)sp * N_Q + qbase) * DHEAD;
#pragma unroll
  for (int nb = 0; nb < 4; ++nb)
#pragma unroll
    for (int r = 0; r < 16; ++r) {
      int row = (r & 3) + 8 * (r >> 2) + 4 * h;
      op[(size_t)row * DHEAD + nb * 32 + c] = (_Float16)acc[nb][r];
    }
}

// ---------------------------------------------------------------------------
// Merge: out[g][dv] = sum_s O_s[g][dv] / sum_s l_s[g]. 131072 threads,
// 8 dv each (16B fp16 loads).
// ---------------------------------------------------------------------------
__global__ void merge_kernel(const _Float16* __restrict__ Opart,
                             const float* __restrict__ Lst,
                             float* __restrict__ out) {
  int tid = blockIdx.x * blockDim.x + threadIdx.x;
  int g = tid >> 4;
  int d0 = (tid & 15) * 8;
  float den = 0.f;
  float num[8] = {0.f, 0.f, 0.f, 0.f, 0.f, 0.f, 0.f, 0.f};
#pragma unroll
  for (int s = 0; s < NSPLIT; ++s) {
    den += Lst[(size_t)s * N_Q + g];
    half8 o = *(const half8*)(Opart + ((size_t)s * N_Q + g) * DHEAD + d0);
#pragma unroll
    for (int j = 0; j < 8; ++j) num[j] += (float)o[j];
  }
  float inv = 1.0f / den;
  floatx4 r0 = (floatx4){num[0] * inv, num[1] * inv, num[2] * inv, num[3] * inv};
  floatx4 r1 = (floatx4){num[4] * inv, num[5] * inv, num[6] * inv, num[7] * inv};
  float* dst = out + (size_t)g * DHEAD + d0;
  *(floatx4*)dst = r0;
  *(floatx4*)(dst + 4) = r1;
}

// ---------------------------------------------------------------------------
extern "C" void kernel_launch(void* const* d_in, const int* in_sizes, int n_in,
                              void* d_out, int out_size, void* d_ws,
                              size_t ws_size, hipStream_t stream) {
  const float* Q = (const float*)d_in[0];
  const float* K = (const float*)d_in[1];
  const float* V = (const float*)d_in[2];
  float* out = (float*)d_out;

  char* ws = (char*)d_ws;
  // Kbc 2MiB | Vtc 2MiB | Opart fp16 16MiB | Lst 256KiB  (= 20.25MiB total)
  unsigned short* Kbc = (unsigned short*)(ws);
  unsigned short* Vtc = (unsigned short*)(ws + (2u << 20));
  _Float16* Opart = (_Float16*)(ws + (4u << 20));
  float* Lst = (float*)(ws + (20u << 20));

  cvt_kernel<<<dim3(1536), dim3(256), 0, stream>>>(K, V, Kbc, Vtc);
  attn_kernel<<<dim3(N_Q / 128, NSPLIT), dim3(256), 0, stream>>>(Q, Kbc, Vtc,
                                                                 Opart, Lst);
  merge_kernel<<<dim3(512), dim3(256), 0, stream>>>(Opart, Lst, out);
}